// Round 6
// baseline (2019.960 us; speedup 1.0000x reference)
//
#include <hip/hip_runtime.h>
#include <hip/hip_bf16.h>
#include <hip/hip_fp16.h>
#include <float.h>
#include <limits.h>

#define NROWS 131072
#define DIM   256
#define NLVL  4
#define KC    1024
#define MARGIN 6.0f
#define CAP   16
#define REC   18        // record: row, cnt, cand[16]

typedef __attribute__((ext_vector_type(8))) short bf16x8;
typedef __attribute__((ext_vector_type(4))) float f32x4;
typedef __attribute__((ext_vector_type(4))) unsigned short us4;

__device__ __forceinline__ unsigned short f2b(float f){
  __hip_bfloat16 h = __float2bfloat16(f);
  return *reinterpret_cast<unsigned short*>(&h);
}

// square with a scheduling barrier so -ffp-contract can never fuse the
// multiply into a following add (numpy materializes cb*cb before summing)
__device__ __forceinline__ float sqb(float x){
  float s = x * x;
  asm volatile("" : "+v"(s));
  return s;
}

// ---------------- prep kernels -----------------------------------------
__global__ void zero4(int* __restrict__ p){
  if (threadIdx.x < 4) p[threadIdx.x] = 0;
}

// bf16 copy of codebooks (phase-A input only)
__global__ void prep_cbb(const float* __restrict__ cb, unsigned short* __restrict__ cbb){
  const int wave = threadIdx.x >> 6, lane = threadIdx.x & 63;
  const int c = blockIdx.x * 4 + wave;                  // 0..4095
  const size_t off = (size_t)c * DIM + lane * 4;
  const float4 v = *reinterpret_cast<const float4*>(cb + off);
  us4 u = { f2b(v.x), f2b(v.y), f2b(v.z), f2b(v.w) };
  *reinterpret_cast<us4*>(cbb + off) = u;
}

// ||c||^2 replicating numpy fp32 pairwise_sum of materialized cb*cb (validated r4)
__global__ void prep_cn(const float* __restrict__ cb, float* __restrict__ cnx){
  const int c = blockIdx.x * 64 + threadIdx.x;          // 0..4095
  const float* p = cb + (size_t)c * DIM;
  float blk[2];
  for (int b = 0; b < 2; ++b){
    float r[8];
#pragma unroll
    for (int j = 0; j < 8; ++j) r[j] = sqb(p[b*128 + j]);
    for (int i = 8; i < 128; i += 8)
#pragma unroll
      for (int j = 0; j < 8; ++j) r[j] += sqb(p[b*128 + i + j]);
    blk[b] = ((r[0]+r[1]) + (r[2]+r[3])) + ((r[4]+r[5]) + (r[6]+r[7]));
  }
  cnx[c] = blk[0] + blk[1];
}

// ---------------- K1: MFMA scoring, scores retained in registers -------
// 32 rows/block, 4 waves; wave w scores centers [w*256,(w+1)*256) over 16
// unrolled MFMA steps. Residual bf16 fragments reconstructed on the fly
// from feat + chosen codewords (exact fp32 chain, validated r4/r5).
template<int LVL>
__global__ __launch_bounds__(256, 2)
void rvq_score(const float* __restrict__ feat,
               const float* __restrict__ cb32,
               const unsigned short* __restrict__ cbb_l,
               const float* __restrict__ cnx_l,
               int* __restrict__ idxw,
               int* __restrict__ ambcnt,
               int* __restrict__ recs)
{
  __shared__ float mlds[4][32];
  __shared__ int rcnt[32];
  __shared__ int rcand[32][CAP];

  const int tid  = threadIdx.x;
  const int wave = tid >> 6, lane = tid & 63;
  const int r16  = lane & 15, quad = lane >> 4;
  const int rowbase = (int)blockIdx.x * 32;

  if (tid < 32) rcnt[tid] = 0;

  // ---- B fragments: exact fp32 residual chain -> bf16 ------------------
  bf16x8 Bf[2][8];
#pragma unroll
  for (int rt = 0; rt < 2; ++rt){
    const int row = rowbase + rt*16 + r16;
    int hist[NLVL];
#pragma unroll
    for (int j = 0; j < LVL; ++j) hist[j] = idxw[j * NROWS + row];
#pragma unroll
    for (int kk = 0; kk < 8; ++kk){
      const int d = kk*32 + quad*8;
      const float* p = feat + (size_t)row * DIM + d;
      float4 f0 = *reinterpret_cast<const float4*>(p);
      float4 f1 = *reinterpret_cast<const float4*>(p + 4);
#pragma unroll
      for (int j = 0; j < LVL; ++j){
        const float* cp = cb32 + ((size_t)j * KC + hist[j]) * DIM + d;
        const float4 c0 = *reinterpret_cast<const float4*>(cp);
        const float4 c1 = *reinterpret_cast<const float4*>(cp + 4);
        f0.x -= c0.x; f0.y -= c0.y; f0.z -= c0.z; f0.w -= c0.w;
        f1.x -= c1.x; f1.y -= c1.y; f1.z -= c1.z; f1.w -= c1.w;
      }
      bf16x8 b;
      b[0]=(short)f2b(f0.x); b[1]=(short)f2b(f0.y); b[2]=(short)f2b(f0.z); b[3]=(short)f2b(f0.w);
      b[4]=(short)f2b(f1.x); b[5]=(short)f2b(f1.y); b[6]=(short)f2b(f1.z); b[7]=(short)f2b(f1.w);
      Bf[rt][kk] = b;
    }
  }

  // ---- MFMA sweep: 16 steps x 16 centers, scores packed fp16 in regs ---
  unsigned su[2][32];
  float mn[2] = { FLT_MAX, FLT_MAX };
  const int cbase = wave * 256;

#pragma unroll
  for (int t = 0; t < 16; ++t){
    const int c0 = cbase + t * 16;
    bf16x8 Af[8];
#pragma unroll
    for (int kk = 0; kk < 8; ++kk)
      Af[kk] = *reinterpret_cast<const bf16x8*>(
          cbb_l + (size_t)(c0 + r16) * DIM + kk*32 + quad*8);
    const float4 cn = *reinterpret_cast<const float4*>(cnx_l + c0 + quad*4);
    f32x4 a0 = {0.f,0.f,0.f,0.f}, a1 = {0.f,0.f,0.f,0.f};
#pragma unroll
    for (int kk = 0; kk < 8; ++kk){
      a0 = __builtin_amdgcn_mfma_f32_16x16x32_bf16(Af[kk], Bf[0][kk], a0, 0, 0, 0);
      a1 = __builtin_amdgcn_mfma_f32_16x16x32_bf16(Af[kk], Bf[1][kk], a1, 0, 0, 0);
    }
    // D: col=lane&15 = row (within tile), row=quad*4+e = center
#pragma unroll
    for (int rt = 0; rt < 2; ++rt){
      const f32x4 a = rt ? a1 : a0;
      const float s0 = cn.x - 2.0f * a[0];
      const float s1 = cn.y - 2.0f * a[1];
      const float s2 = cn.z - 2.0f * a[2];
      const float s3 = cn.w - 2.0f * a[3];
      mn[rt] = fminf(mn[rt], fminf(fminf(s0, s1), fminf(s2, s3)));
      su[rt][t*2]   = __builtin_bit_cast(unsigned, __builtin_amdgcn_cvt_pkrtz(s0, s1));
      su[rt][t*2+1] = __builtin_bit_cast(unsigned, __builtin_amdgcn_cvt_pkrtz(s2, s3));
    }
  }

  // ---- per-row min across quads and waves ------------------------------
#pragma unroll
  for (int rt = 0; rt < 2; ++rt){
    float m = mn[rt];
    m = fminf(m, __shfl_xor(m, 16));
    m = fminf(m, __shfl_xor(m, 32));
    if (quad == 0) mlds[wave][rt*16 + r16] = m;
  }
  __syncthreads();

  float thr[2];
#pragma unroll
  for (int rt = 0; rt < 2; ++rt){
    const int row = rt*16 + r16;
    thr[rt] = fminf(fminf(mlds[0][row], mlds[1][row]),
                    fminf(mlds[2][row], mlds[3][row])) + MARGIN;
  }

  // ---- in-register margin scan -> LDS candidate lists ------------------
#pragma unroll
  for (int rt = 0; rt < 2; ++rt){
    const int row = rt*16 + r16;
#pragma unroll
    for (int t = 0; t < 16; ++t){
#pragma unroll
      for (int w = 0; w < 2; ++w){
        const float2 f = __half22float2(__builtin_bit_cast(__half2, su[rt][t*2 + w]));
        if (f.x <= thr[rt]){
          const int p = atomicAdd(&rcnt[row], 1);
          if (p < CAP) rcand[row][p] = cbase + t*16 + quad*4 + w*2;
        }
        if (f.y <= thr[rt]){
          const int p = atomicAdd(&rcnt[row], 1);
          if (p < CAP) rcand[row][p] = cbase + t*16 + quad*4 + w*2 + 1;
        }
      }
    }
  }
  __syncthreads();

  // ---- classify & emit --------------------------------------------------
  if (tid < 32){
    const int c = rcnt[tid];
    const int grow = rowbase + tid;
    if (c == 1){
      idxw[LVL * NROWS + grow] = rcand[tid][0];
    } else {
      const int pos = atomicAdd(&ambcnt[LVL], 1);
      int* rp = recs + (size_t)pos * REC;
      rp[0] = grow; rp[1] = c;
      const int cc = c < CAP ? c : CAP;
      for (int q = 0; q < cc; ++q) rp[2+q] = rcand[tid][q];
    }
  }
}

// ---------------- K2: exact np-fp32 re-rank of compacted rows ----------
// (validated r5) 16 lanes/row, grid-stride over records.
template<int LVL>
__global__ __launch_bounds__(256)
void rvq_rerank(const float* __restrict__ feat,
                const float* __restrict__ cb32,
                const float* __restrict__ cnx_l,
                int* __restrict__ idxw,
                const int* __restrict__ ambcnt,
                const int* __restrict__ recs)
{
  __shared__ float rres[16][260];
  const int tid = threadIdx.x;
  const int g = tid >> 4, q = tid & 15;
  const int cnt = ambcnt[LVL];
  const float* cbl = cb32 + (size_t)LVL * KC * DIM;

  for (int r = blockIdx.x * 16 + g; r < cnt; r += gridDim.x * 16){
    const int* rp = recs + (size_t)r * REC;
    const int grow = rp[0];
    const int c = rp[1];

    // exact fp32-chain residual (lane q owns d = q*16..q*16+15)
#pragma unroll
    for (int i4 = 0; i4 < 4; ++i4){
      const int d = q*16 + i4*4;
      float4 v = *reinterpret_cast<const float4*>(feat + (size_t)grow * DIM + d);
#pragma unroll
      for (int j2 = 0; j2 < LVL; ++j2){
        const int kj = idxw[(size_t)j2 * NROWS + grow];
        const float4 cv = *reinterpret_cast<const float4*>(
            cb32 + ((size_t)j2 * KC + kj) * DIM + d);
        v.x -= cv.x; v.y -= cv.y; v.z -= cv.z; v.w -= cv.w;
      }
      *reinterpret_cast<float4*>(&rres[g][d]) = v;
    }

    float bs = FLT_MAX; int bi = INT_MAX;
    if (c <= CAP){
      if (q < c){
        const int ci = rp[2+q];
        float a = 0.f;
        for (int d4 = 0; d4 < 64; ++d4){
          const float4 cv = *reinterpret_cast<const float4*>(cbl + (size_t)ci * DIM + d4*4);
          const float4 rv = *reinterpret_cast<const float4*>(&rres[g][d4*4]);
          a = fmaf(rv.x, cv.x, a); a = fmaf(rv.y, cv.y, a);
          a = fmaf(rv.z, cv.z, a); a = fmaf(rv.w, cv.w, a);
        }
        bs = cnx_l[ci] - 2.0f * a; bi = ci;
      }
    } else {
      // overflow: brute-force all 1024 centers (exact chain)
      for (int t = 0; t < 64; ++t){
        const int ci = q + 16*t;
        float a = 0.f;
        for (int d4 = 0; d4 < 64; ++d4){
          const float4 cv = *reinterpret_cast<const float4*>(cbl + (size_t)ci * DIM + d4*4);
          const float4 rv = *reinterpret_cast<const float4*>(&rres[g][d4*4]);
          a = fmaf(rv.x, cv.x, a); a = fmaf(rv.y, cv.y, a);
          a = fmaf(rv.z, cv.z, a); a = fmaf(rv.w, cv.w, a);
        }
        const float sc = cnx_l[ci] - 2.0f * a;
        if (sc < bs){ bs = sc; bi = ci; }
      }
    }
#pragma unroll
    for (int m = 1; m < 16; m <<= 1){
      const float ob = __shfl_xor(bs, m); const int oi = __shfl_xor(bi, m);
      if (ob < bs || (ob == bs && oi < bi)){ bs = ob; bi = oi; }
    }
    if (q == 0) idxw[(size_t)LVL * NROWS + grow] = bi;
  }
}

// ---------------- K3: final output = q0+q1+q2+q3 (r5-validated order) --
__global__ __launch_bounds__(256)
void rvq_out(const float* __restrict__ cb32,
             const int* __restrict__ idxw,
             float* __restrict__ out)
{
  const int tid = threadIdx.x;
  const int row = tid >> 4, sub = tid & 15;
  const size_t n = (size_t)blockIdx.x * 16 + row;
  int hist[NLVL];
#pragma unroll
  for (int j2 = 0; j2 < 4; ++j2) hist[j2] = idxw[(size_t)j2 * NROWS + n];
#pragma unroll
  for (int i = 0; i < 4; ++i){
    const int d = sub*4 + i*64;
    float4 a = *reinterpret_cast<const float4*>(
        cb32 + ((size_t)0 * KC + hist[0]) * DIM + d);
#pragma unroll
    for (int j2 = 1; j2 < 4; ++j2){
      const float4 qv = *reinterpret_cast<const float4*>(
          cb32 + ((size_t)j2 * KC + hist[j2]) * DIM + d);
      a.x += qv.x; a.y += qv.y; a.z += qv.z; a.w += qv.w;
    }
    *reinterpret_cast<float4*>(out + n*DIM + d) = a;
  }
}

extern "C" void kernel_launch(void* const* d_in, const int* in_sizes, int n_in,
                              void* d_out, int out_size, void* d_ws, size_t ws_size,
                              hipStream_t stream){
  const float* feat = (const float*)d_in[0];
  const float* cb32 = (const float*)d_in[1];
  float* out = (float*)d_out;

  char* ws = (char*)d_ws;
  float* cnx  = (float*)(ws);                               // 16 KB
  int*   amb  = (int*)(ws + 16384);                         // 4 ints (padded)
  unsigned short* cbb = (unsigned short*)(ws + 32768);      // 2 MB
  int*   idxw = (int*)(ws + 32768 + 2097152);               // 2 MB
  int*   recs = (int*)(ws + 32768 + 2097152 + 2097152);     // ~9.5 MB

  zero4<<<1, 64, 0, stream>>>(amb);
  prep_cbb<<<1024, 256, 0, stream>>>(cb32, cbb);
  prep_cn<<<64, 64, 0, stream>>>(cb32, cnx);

#define LVL_STEP(L) \
  rvq_score<L><<<4096, 256, 0, stream>>>(feat, cb32, cbb + (size_t)L*KC*DIM, \
      cnx + L*KC, idxw, amb, recs); \
  rvq_rerank<L><<<512, 256, 0, stream>>>(feat, cb32, cnx + L*KC, idxw, amb, recs);

  LVL_STEP(0)
  LVL_STEP(1)
  LVL_STEP(2)
  LVL_STEP(3)
#undef LVL_STEP

  rvq_out<<<8192, 256, 0, stream>>>(cb32, idxw, out);
}